// Round 1
// baseline (8307.545 us; speedup 1.0000x reference)
//
#include <hip/hip_runtime.h>
#include <hip/hip_bf16.h>
#include <cstdint>

// Problem constants
#define BV 32000
#define BE 256
#define BU 512
#define BD 512
#define BB 32
#define BT 64
// 4U = 2048, 2U = 1024, K decoder = 1536

// ---------- bf16 pack helpers (RNE) ----------
__device__ __forceinline__ uint32_t bf1(float x) {
  uint32_t u = __float_as_uint(x);
  return (u + 0x7fffu + ((u >> 16) & 1u)) >> 16;
}
__device__ __forceinline__ uint32_t bpack(float lo, float hi) {
  return bf1(lo) | (bf1(hi) << 16);
}
__device__ __forceinline__ float blo(uint32_t u) { return __uint_as_float(u << 16); }
__device__ __forceinline__ float bhi(uint32_t u) { return __uint_as_float(u & 0xffff0000u); }

__device__ __forceinline__ float sigm(float x) { return 1.f / (1.f + __expf(-x)); }

// =====================================================================
// K1: embedding gather + Xf = xe@Wxf + bf, Xb = xe@Wxb + bb
// Output layout X[t][c][b]  (c in 0..2047), so encoder steps read [c][b] tiles.
// grid (32 col-tiles of 128 over 4096 combined, 64 t), 256 thr. fp32.
// =====================================================================
__global__ __launch_bounds__(256) void k1_embed_gemm(
    const int* __restrict__ x, const float* __restrict__ emb,
    const float* __restrict__ Wxf, const float* __restrict__ Wxb,
    const float* __restrict__ bfv, const float* __restrict__ bbv,
    float* __restrict__ Xf, float* __restrict__ Xb)
{
  __shared__ float As[32 * 260];   // [b][k] pad 260
  __shared__ float Bs[32 * 128];   // [k][c]
  __shared__ int xid[32];
  const int t = threadIdx.x;
  const int ty = blockIdx.y;            // time index
  const int c0 = blockIdx.x * 128;      // 0..4095
  if (t < 32) xid[t] = x[t * BT + ty];
  __syncthreads();
  // stage A (32 x 256)
  for (int i = 0; i < 8; ++i) {
    int f4 = t + 256 * i;               // 0..2047
    int r = f4 >> 6, k4 = (f4 & 63) << 2;
    float4 v = *(const float4*)(emb + (size_t)xid[r] * BE + k4);
    *(float4*)(&As[r * 260 + k4]) = v;
  }
  const int isB = (c0 >= 2048);
  const float* Wsrc = isB ? Wxb : Wxf;
  const float* bias = isB ? bbv : bfv;
  const int cbase = c0 & 2047;
  float acc[4][4] = {};
  const int rq = t >> 5;   // rows 4rq..4rq+3
  const int cq = t & 31;   // cols 4cq..4cq+3 (of 128)
  for (int kc = 0; kc < 8; ++kc) {
    int k0 = kc * 32;
    __syncthreads();
    for (int i = 0; i < 4; ++i) {
      int f4 = t + 256 * i;             // 0..1023
      int k = f4 >> 5, c4 = (f4 & 31) << 2;
      *(float4*)(&Bs[k * 128 + c4]) =
          *(const float4*)(Wsrc + (size_t)(k0 + k) * 2048 + cbase + c4);
    }
    __syncthreads();
#pragma unroll
    for (int kk = 0; kk < 32; ++kk) {
      float a0 = As[(4 * rq + 0) * 260 + k0 + kk];
      float a1 = As[(4 * rq + 1) * 260 + k0 + kk];
      float a2 = As[(4 * rq + 2) * 260 + k0 + kk];
      float a3 = As[(4 * rq + 3) * 260 + k0 + kk];
      float4 b = *(const float4*)(&Bs[kk * 128 + 4 * cq]);
      acc[0][0] += a0 * b.x; acc[0][1] += a0 * b.y; acc[0][2] += a0 * b.z; acc[0][3] += a0 * b.w;
      acc[1][0] += a1 * b.x; acc[1][1] += a1 * b.y; acc[1][2] += a1 * b.z; acc[1][3] += a1 * b.w;
      acc[2][0] += a2 * b.x; acc[2][1] += a2 * b.y; acc[2][2] += a2 * b.z; acc[2][3] += a2 * b.w;
      acc[3][0] += a3 * b.x; acc[3][1] += a3 * b.y; acc[3][2] += a3 * b.z; acc[3][3] += a3 * b.w;
    }
  }
  float* Xout = isB ? Xb : Xf;
  for (int i = 0; i < 4; ++i) {
    int c = cbase + 4 * cq + i;
    float bi = bias[c];
    for (int j = 0; j < 4; ++j) {
      int b_ = 4 * rq + j;
      Xout[((size_t)ty * 2048 + c) * 32 + b_] = acc[j][i] + bi;
    }
  }
}

// =====================================================================
// K2: one encoder step, both directions. 256 blocks (dir = bid>>7), 256 thr.
// Each block: 4 units (16 z-cols) of z = X[t] + h@Wh, then LSTM pointwise.
// h and Wh staged to LDS as packed bf16 k-pairs.
// =====================================================================
__global__ __launch_bounds__(256) void k2_enc_step(
    const float* __restrict__ Xf, const float* __restrict__ Xb,
    const float* __restrict__ Whf, const float* __restrict__ Whb,
    const float* __restrict__ hfi, float* __restrict__ hfo,
    const float* __restrict__ hbi, float* __restrict__ hbo,
    float* __restrict__ cf, float* __restrict__ cb,
    float* __restrict__ a_out, int step)
{
  __shared__ uint32_t hTp[256 * 32];   // [k2][r]
  __shared__ uint32_t Wsp[256 * 16];   // [k2][c], c = gate*4+j
  __shared__ float zx[16 * 33];        // [c][r]
  __shared__ float zbuf[32 * 17];      // [r][c]
  const int t = threadIdx.x;
  const int dir = blockIdx.x >> 7;
  const int blk = blockIdx.x & 127;
  const int u0 = blk * 4;
  const float* XF = dir ? Xb : Xf;
  const float* Wh = dir ? Whb : Whf;
  const float* hin = dir ? hbi : hfi;
  float* hout = dir ? hbo : hfo;
  float* cst = dir ? cb : cf;
  const int ta = dir ? (BT - 1 - step) : step;

  // stage h (512x32 fp32 [k][r]) -> packed pairs
  for (int i = 0; i < 8; ++i) {
    int p = t + 256 * i;                 // 0..2047
    int k2 = p >> 3, r4 = (p & 7) << 2;
    float4 va = *(const float4*)(hin + (size_t)(2 * k2) * 32 + r4);
    float4 vb = *(const float4*)(hin + (size_t)(2 * k2 + 1) * 32 + r4);
    uint32_t* w = &hTp[k2 * 32 + r4];
    w[0] = bpack(va.x, vb.x); w[1] = bpack(va.y, vb.y);
    w[2] = bpack(va.z, vb.z); w[3] = bpack(va.w, vb.w);
  }
  // stage Wh slice: cols gate*512+u0+j
  for (int i = 0; i < 4; ++i) {
    int p = t + 256 * i;                 // 0..1023
    int k2 = p >> 2, g = p & 3;
    const float4 va = *(const float4*)(Wh + (size_t)(2 * k2) * 2048 + g * 512 + u0);
    const float4 vb = *(const float4*)(Wh + (size_t)(2 * k2 + 1) * 2048 + g * 512 + u0);
    uint32_t* w = &Wsp[k2 * 16 + g * 4];
    w[0] = bpack(va.x, vb.x); w[1] = bpack(va.y, vb.y);
    w[2] = bpack(va.z, vb.z); w[3] = bpack(va.w, vb.w);
  }
  // stage X[t] tile (z init, bias already folded in K1)
  for (int i = 0; i < 2; ++i) {
    int p = t + 256 * i;                 // 0..511
    int c = p >> 5, r = p & 31;
    int col = (c >> 2) * 512 + u0 + (c & 3);
    zx[c * 33 + r] = XF[((size_t)ta * 2048 + col) * 32 + r];
  }
  __syncthreads();
  const int r = t & 31, cc = t >> 5;     // cc 0..7
  float acc0 = zx[cc * 33 + r];
  float acc1 = zx[(cc + 8) * 33 + r];
#pragma unroll 8
  for (int k2 = 0; k2 < 256; ++k2) {
    uint32_t ua = hTp[k2 * 32 + r];
    uint32_t b0 = Wsp[k2 * 16 + cc];
    uint32_t b1 = Wsp[k2 * 16 + cc + 8];
    float a0 = blo(ua), a1 = bhi(ua);
    acc0 += a0 * blo(b0); acc0 += a1 * bhi(b0);
    acc1 += a0 * blo(b1); acc1 += a1 * bhi(b1);
  }
  zbuf[r * 17 + cc] = acc0;
  zbuf[r * 17 + cc + 8] = acc1;
  __syncthreads();
  if (t < 128) {
    int rr = t & 31, j = t >> 5;         // j 0..3
    float zi = zbuf[rr * 17 + j];
    float zf = zbuf[rr * 17 + 4 + j];
    float zg = zbuf[rr * 17 + 8 + j];
    float zo = zbuf[rr * 17 + 12 + j];
    int u = u0 + j;
    float cold = cst[u * 32 + rr];
    float cn = sigm(zf) * cold + sigm(zi) * tanhf(zg);
    float h = sigm(zo) * tanhf(cn);
    cst[u * 32 + rr] = cn;
    hout[u * 32 + rr] = h;
    a_out[((size_t)rr * BT + ta) * 1024 + dir * 512 + u] = h;
  }
}

// =====================================================================
// K5: aw1[m][j] = a[m]@W1[:1024,j] + b1[j], m = b*64+t, padded to 16 cols.
// =====================================================================
__global__ __launch_bounds__(256) void k5_aw1(
    const float* __restrict__ a, const float* __restrict__ W1,
    const float* __restrict__ b1, float* __restrict__ aw1)
{
  __shared__ float ar[1024];
  __shared__ float ps[16 * 17];
  const int t = threadIdx.x;
  for (int m = blockIdx.x; m < 2048; m += gridDim.x) {
    __syncthreads();
    *(float4*)(&ar[t * 4]) = *(const float4*)(a + (size_t)m * 1024 + t * 4);
    __syncthreads();
    int j = t & 15, part = t >> 4;
    int jj = j < 10 ? j : 0;
    float s = 0.f;
#pragma unroll 8
    for (int k = part * 64; k < part * 64 + 64; ++k) s += ar[k] * W1[k * 10 + jj];
    ps[part * 17 + j] = s;
    __syncthreads();
    if (t < 16) {
      float sum = 0.f;
      if (t < 10) {
        for (int p = 0; p < 16; ++p) sum += ps[p * 17 + t];
        sum += b1[t];
      }
      aw1[m * 16 + t] = sum;
    }
  }
}

// =====================================================================
// K3: attention for one decoder step: hW1 (redundant per block), e scores,
// softmax over T, then ctx slice (16 cols per block). grid 64 x 256.
// =====================================================================
__global__ __launch_bounds__(256) void k3_attn(
    const float* __restrict__ a, const float* __restrict__ aw1,
    const float* __restrict__ W1, const float* __restrict__ W2,
    const float* __restrict__ b2, const float* __restrict__ hdT,
    float* __restrict__ ctx)
{
  __shared__ float W1s[512 * 12];
  __shared__ float ph[8 * 32 * 12];
  __shared__ float hw1[32 * 12];
  __shared__ float esc[32 * 65];
  __shared__ float pm[32 * 9];
  __shared__ float mrow[32], srow[32];
  __shared__ float w2s[12];
  const int t = threadIdx.x;
  for (int i = 0; i < 24; ++i) {
    int p = t + 256 * i;                 // 0..6143
    int k = p / 12, j = p % 12;
    W1s[p] = (j < 10) ? W1[(1024 + k) * 10 + j] : 0.f;
  }
  if (t < 10) w2s[t] = W2[t];
  else if (t < 12) w2s[t] = 0.f;
  __syncthreads();
  // hW1 partials: thread (r, kp)
  {
    const int r = t & 31, kp = t >> 5;
    float acc[10] = {};
#pragma unroll 4
    for (int k = kp * 64; k < kp * 64 + 64; ++k) {
      float hv = hdT[k * 32 + r];
#pragma unroll
      for (int j = 0; j < 10; ++j) acc[j] += hv * W1s[k * 12 + j];
    }
#pragma unroll
    for (int j = 0; j < 10; ++j) ph[(kp * 32 + r) * 12 + j] = acc[j];
  }
  __syncthreads();
  if (t < 320) {
    int r = t & 31, j = t >> 5;          // j 0..9
    float s = 0.f;
#pragma unroll
    for (int p = 0; p < 8; ++p) s += ph[(p * 32 + r) * 12 + j];
    hw1[r * 12 + j] = s;
  }
  __syncthreads();
  // e scores
  const float b2v = b2[0];
  for (int p = 0; p < 8; ++p) {
    int idx = t + 256 * p;               // 0..2047
    int rr = idx >> 6, tt = idx & 63;
    const float4* aw = (const float4*)(aw1 + (size_t)idx * 16);
    float4 q0 = aw[0], q1 = aw[1], q2 = aw[2];
    const float* hw = &hw1[rr * 12];
    float e = b2v;
    e += tanhf(q0.x + hw[0]) * w2s[0];
    e += tanhf(q0.y + hw[1]) * w2s[1];
    e += tanhf(q0.z + hw[2]) * w2s[2];
    e += tanhf(q0.w + hw[3]) * w2s[3];
    e += tanhf(q1.x + hw[4]) * w2s[4];
    e += tanhf(q1.y + hw[5]) * w2s[5];
    e += tanhf(q1.z + hw[6]) * w2s[6];
    e += tanhf(q1.w + hw[7]) * w2s[7];
    e += tanhf(q2.x + hw[8]) * w2s[8];
    e += tanhf(q2.y + hw[9]) * w2s[9];
    esc[rr * 65 + tt] = fmaxf(e, 0.f);
  }
  __syncthreads();
  {
    int r = t & 31, part = t >> 5;
    float m = -1e30f;
    for (int i = 0; i < 8; ++i) m = fmaxf(m, esc[r * 65 + part * 8 + i]);
    pm[r * 9 + part] = m;
  }
  __syncthreads();
  if (t < 32) {
    float m = pm[t * 9];
    for (int p = 1; p < 8; ++p) m = fmaxf(m, pm[t * 9 + p]);
    mrow[t] = m;
  }
  __syncthreads();
  {
    int r = t & 31, part = t >> 5;
    float m = mrow[r];
    float s = 0.f;
    for (int i = 0; i < 8; ++i) s += __expf(esc[r * 65 + part * 8 + i] - m);
    pm[r * 9 + part] = s;
  }
  __syncthreads();
  if (t < 32) {
    float s = 0.f;
    for (int p = 0; p < 8; ++p) s += pm[t * 9 + p];
    srow[t] = 1.f / s;
  }
  __syncthreads();
  for (int p = 0; p < 8; ++p) {
    int idx = t + 256 * p;
    int rr = idx >> 6, tt = idx & 63;
    esc[rr * 65 + tt] = __expf(esc[rr * 65 + tt] - mrow[rr]) * srow[rr];
  }
  __syncthreads();
  // ctx slice: 16 cols for this block
  {
    const int c = blockIdx.x * 16 + (t & 15);
    const int rr = t >> 4;               // 0..15
    float acc0 = 0.f, acc1 = 0.f;
    for (int tt = 0; tt < 64; ++tt) {
      float s0 = esc[rr * 65 + tt];
      float s1 = esc[(rr + 16) * 65 + tt];
      acc0 += s0 * a[((size_t)rr * 64 + tt) * 1024 + c];
      acc1 += s1 * a[((size_t)(rr + 16) * 64 + tt) * 1024 + c];
    }
    ctx[rr * 1024 + c] = acc0;
    ctx[(rr + 16) * 1024 + c] = acc1;
  }
}

// =====================================================================
// K4: decoder LSTM step: z = [ctx|h]@[Wxd;Whd] + bd (K=1536), pointwise,
// write h (transposed [k][r]) and Hs[step]. 256 blocks x 2 units, 256 thr.
// =====================================================================
__global__ __launch_bounds__(256) void k4_dec_step(
    const float* __restrict__ ctx, const float* __restrict__ hdT_in,
    const float* __restrict__ Wxd, const float* __restrict__ Whd,
    const float* __restrict__ bd, float* __restrict__ hdT_out,
    float* __restrict__ cd, float* __restrict__ Hs, int step)
{
  __shared__ uint32_t ATp[128 * 33];     // [k2][r] per 256-k chunk
  __shared__ uint32_t Wsp[768 * 8];      // [k2][c] whole K
  __shared__ float zbuf[32 * 9];
  const int t = threadIdx.x;
  const int u0 = blockIdx.x * 2;
  // stage W slice packed: c = gate*2 + j
  for (int i = 0; i < 24; ++i) {
    int p = t + 256 * i;                 // 0..6143
    int c = p & 7, k2 = p >> 3;
    int col = (c >> 1) * 512 + u0 + (c & 1);
    int k = 2 * k2;
    float v0, v1;
    if (k < 1024) {
      v0 = Wxd[(size_t)k * 2048 + col];
      v1 = Wxd[(size_t)(k + 1) * 2048 + col];
    } else {
      v0 = Whd[(size_t)(k - 1024) * 2048 + col];
      v1 = Whd[(size_t)(k - 1023) * 2048 + col];
    }
    Wsp[k2 * 8 + c] = bpack(v0, v1);
  }
  const int r = t & 31, cc = t >> 5;     // cc 0..7
  float acc = 0.f;
  for (int ch = 0; ch < 6; ++ch) {
    __syncthreads();
    int kb = ch * 256;
    if (kb < 1024) {
      for (int i = 0; i < 8; ++i) {
        int p = t + 256 * i;             // 0..2047
        int rr = p >> 6, k8 = p & 63;
        float4 v = *(const float4*)(ctx + (size_t)rr * 1024 + kb + k8 * 4);
        ATp[(2 * k8) * 33 + rr] = bpack(v.x, v.y);
        ATp[(2 * k8 + 1) * 33 + rr] = bpack(v.z, v.w);
      }
    } else {
      for (int i = 0; i < 4; ++i) {
        int p = t + 256 * i;             // 0..1023
        int k2l = p >> 3, r4 = (p & 7) << 2;
        int k = (kb - 1024) + 2 * k2l;
        float4 va = *(const float4*)(hdT_in + (size_t)k * 32 + r4);
        float4 vb = *(const float4*)(hdT_in + (size_t)(k + 1) * 32 + r4);
        uint32_t* w = &ATp[k2l * 33 + r4];
        w[0] = bpack(va.x, vb.x); w[1] = bpack(va.y, vb.y);
        w[2] = bpack(va.z, vb.z); w[3] = bpack(va.w, vb.w);
      }
    }
    __syncthreads();
    const uint32_t* wp = &Wsp[(kb >> 1) * 8];
#pragma unroll 8
    for (int k2 = 0; k2 < 128; ++k2) {
      uint32_t ua = ATp[k2 * 33 + r];
      uint32_t ub = wp[k2 * 8 + cc];
      acc += blo(ua) * blo(ub);
      acc += bhi(ua) * bhi(ub);
    }
  }
  int col = (cc >> 1) * 512 + u0 + (cc & 1);
  zbuf[r * 9 + cc] = acc + bd[col];
  __syncthreads();
  if (t < 64) {
    int rr = t & 31, j = t >> 5;         // j 0..1
    int u = u0 + j;
    float zi = zbuf[rr * 9 + j];
    float zf = zbuf[rr * 9 + 2 + j];
    float zg = zbuf[rr * 9 + 4 + j];
    float zo = zbuf[rr * 9 + 6 + j];
    float cold = cd[u * 32 + rr];
    float cn = sigm(zf) * cold + sigm(zi) * tanhf(zg);
    float h = sigm(zo) * tanhf(cn);
    cd[u * 32 + rr] = cn;
    hdT_out[u * 32 + rr] = h;
    Hs[((size_t)step * 32 + rr) * 512 + u] = h;
  }
}

// =====================================================================
// K6: logits = Hs[2048,512] @ Wo[512,32000] + bo -> d_out (fp32 acc,
// packed-bf16 LDS operands). grid (125 n-tiles x 32 m-tiles), 256 thr,
// 64x256 tile, 8x8 per thread.
// =====================================================================
__global__ __launch_bounds__(256) void k6_logits(
    const float* __restrict__ Hs, const float* __restrict__ Wo,
    const float* __restrict__ bo, float* __restrict__ out)
{
  __shared__ uint32_t Ap[16 * 64];       // [k2][m]
  __shared__ uint32_t Bp[16 * 256];      // [k2][n]
  const int t = threadIdx.x;
  const int m0 = blockIdx.y * 64;
  const int n0 = blockIdx.x * 256;
  const int rg = t >> 5;                 // 0..7
  const int cg = t & 31;                 // 0..31
  float acc[2][2][4][4] = {};
  for (int kc = 0; kc < 16; ++kc) {
    int k0 = kc * 32;
    __syncthreads();
    for (int i = 0; i < 2; ++i) {
      int p = t + 256 * i;               // 0..511
      int m = p >> 3, k8 = p & 7;
      float4 v = *(const float4*)(Hs + (size_t)(m0 + m) * 512 + k0 + k8 * 4);
      Ap[(2 * k8) * 64 + m] = bpack(v.x, v.y);
      Ap[(2 * k8 + 1) * 64 + m] = bpack(v.z, v.w);
    }
    for (int i = 0; i < 4; ++i) {
      int p = t + 256 * i;               // 0..1023
      int k2 = p >> 6, n4 = (p & 63) << 2;
      float4 va = *(const float4*)(Wo + (size_t)(k0 + 2 * k2) * 32000 + n0 + n4);
      float4 vb = *(const float4*)(Wo + (size_t)(k0 + 2 * k2 + 1) * 32000 + n0 + n4);
      uint32_t* w = &Bp[k2 * 256 + n4];
      w[0] = bpack(va.x, vb.x); w[1] = bpack(va.y, vb.y);
      w[2] = bpack(va.z, vb.z); w[3] = bpack(va.w, vb.w);
    }
    __syncthreads();
#pragma unroll
    for (int k2 = 0; k2 < 16; ++k2) {
      uint4 va0 = *(const uint4*)(&Ap[k2 * 64 + 4 * rg]);
      uint4 va1 = *(const uint4*)(&Ap[k2 * 64 + 32 + 4 * rg]);
      uint4 vb0 = *(const uint4*)(&Bp[k2 * 256 + 4 * cg]);
      uint4 vb1 = *(const uint4*)(&Bp[k2 * 256 + 128 + 4 * cg]);
      float a0l[4], a0h[4], a1l[4], a1h[4], b0l[4], b0h[4], b1l[4], b1h[4];
      a0l[0] = blo(va0.x); a0h[0] = bhi(va0.x); a0l[1] = blo(va0.y); a0h[1] = bhi(va0.y);
      a0l[2] = blo(va0.z); a0h[2] = bhi(va0.z); a0l[3] = blo(va0.w); a0h[3] = bhi(va0.w);
      a1l[0] = blo(va1.x); a1h[0] = bhi(va1.x); a1l[1] = blo(va1.y); a1h[1] = bhi(va1.y);
      a1l[2] = blo(va1.z); a1h[2] = bhi(va1.z); a1l[3] = blo(va1.w); a1h[3] = bhi(va1.w);
      b0l[0] = blo(vb0.x); b0h[0] = bhi(vb0.x); b0l[1] = blo(vb0.y); b0h[1] = bhi(vb0.y);
      b0l[2] = blo(vb0.z); b0h[2] = bhi(vb0.z); b0l[3] = blo(vb0.w); b0h[3] = bhi(vb0.w);
      b1l[0] = blo(vb1.x); b1h[0] = bhi(vb1.x); b1l[1] = blo(vb1.y); b1h[1] = bhi(vb1.y);
      b1l[2] = blo(vb1.z); b1h[2] = bhi(vb1.z); b1l[3] = blo(vb1.w); b1h[3] = bhi(vb1.w);
#pragma unroll
      for (int i = 0; i < 4; ++i)
#pragma unroll
        for (int j = 0; j < 4; ++j) {
          acc[0][0][i][j] += a0l[i] * b0l[j] + a0h[i] * b0h[j];
          acc[0][1][i][j] += a0l[i] * b1l[j] + a0h[i] * b1h[j];
          acc[1][0][i][j] += a1l[i] * b0l[j] + a1h[i] * b0h[j];
          acc[1][1][i][j] += a1l[i] * b1l[j] + a1h[i] * b1h[j];
        }
    }
  }
#pragma unroll
  for (int rh = 0; rh < 2; ++rh)
#pragma unroll
    for (int i = 0; i < 4; ++i) {
      int m = m0 + rh * 32 + 4 * rg + i;
      int b_ = m & 31, tt = m >> 5;      // Hs row = step*32 + b
      size_t rowbase = ((size_t)b_ * 64 + tt) * 32000;
#pragma unroll
      for (int chh = 0; chh < 2; ++chh) {
        int c = n0 + chh * 128 + 4 * cg;
        float4 bb = *(const float4*)(bo + c);
        float4 o;
        o.x = acc[rh][chh][i][0] + bb.x;
        o.y = acc[rh][chh][i][1] + bb.y;
        o.z = acc[rh][chh][i][2] + bb.z;
        o.w = acc[rh][chh][i][3] + bb.w;
        *(float4*)(out + rowbase + c) = o;
      }
    }
}

// =====================================================================
// K7: in-place row softmax over V=32000 (2048 rows). Re-reads hit L2.
// =====================================================================
__global__ __launch_bounds__(256) void k7_softmax(float* __restrict__ out)
{
  __shared__ float red[256];
  const int t = threadIdx.x;
  for (int row = blockIdx.x; row < 2048; row += gridDim.x) {
    float* p = out + (size_t)row * 32000;
    float m = -1e30f;
    for (int i = t; i < 8000; i += 256) {
      float4 v = *(const float4*)(p + i * 4);
      m = fmaxf(m, fmaxf(fmaxf(v.x, v.y), fmaxf(v.z, v.w)));
    }
    red[t] = m;
    __syncthreads();
    for (int s = 128; s > 0; s >>= 1) {
      if (t < s) red[t] = fmaxf(red[t], red[t + s]);
      __syncthreads();
    }
    m = red[0];
    __syncthreads();
    float sum = 0.f;
    for (int i = t; i < 8000; i += 256) {
      float4 v = *(const float4*)(p + i * 4);
      sum += __expf(v.x - m) + __expf(v.y - m) + __expf(v.z - m) + __expf(v.w - m);
    }
    red[t] = sum;
    __syncthreads();
    for (int s = 128; s > 0; s >>= 1) {
      if (t < s) red[t] += red[t + s];
      __syncthreads();
    }
    float inv = 1.f / red[0];
    __syncthreads();
    for (int i = t; i < 8000; i += 256) {
      float4 v = *(const float4*)(p + i * 4);
      v.x = __expf(v.x - m) * inv;
      v.y = __expf(v.y - m) * inv;
      v.z = __expf(v.z - m) * inv;
      v.w = __expf(v.w - m) * inv;
      *(float4*)(p + i * 4) = v;
    }
    __syncthreads();
  }
}

// =====================================================================
extern "C" void kernel_launch(void* const* d_in, const int* in_sizes, int n_in,
                              void* d_out, int out_size, void* d_ws, size_t ws_size,
                              hipStream_t stream)
{
  const int* x = (const int*)d_in[0];
  const float* emb = (const float*)d_in[1];
  const float* Wxf = (const float*)d_in[2];
  const float* Whf = (const float*)d_in[3];
  const float* bfv = (const float*)d_in[4];
  const float* Wxb = (const float*)d_in[5];
  const float* Whb = (const float*)d_in[6];
  const float* bbv = (const float*)d_in[7];
  const float* W1 = (const float*)d_in[8];
  const float* b1 = (const float*)d_in[9];
  const float* W2 = (const float*)d_in[10];
  const float* b2 = (const float*)d_in[11];
  const float* Wxd = (const float*)d_in[12];
  const float* Whd = (const float*)d_in[13];
  const float* bd = (const float*)d_in[14];
  const float* Wo = (const float*)d_in[15];
  const float* bo = (const float*)d_in[16];

  float* ws = (float*)d_ws;
  // states (zeroed each call): hfT0,hfT1,hbT0,hbT1,cf,cb,hdT0,hdT1,cd
  float* st = ws;
  float* hfT0 = st + 0 * 16384;
  float* hfT1 = st + 1 * 16384;
  float* hbT0 = st + 2 * 16384;
  float* hbT1 = st + 3 * 16384;
  float* cfT  = st + 4 * 16384;
  float* cbT  = st + 5 * 16384;
  float* hdT0 = st + 6 * 16384;
  float* hdT1 = st + 7 * 16384;
  float* cdT  = st + 8 * 16384;
  float* Xf  = ws + 147456;              // [64][2048][32]
  float* Xb  = Xf + 4194304;
  float* a   = Xb + 4194304;             // [32][64][1024]
  float* aw1 = a + 2097152;              // [2048][16]
  float* ctx = aw1 + 32768;              // [32][1024]
  float* Hs  = ctx + 32768;              // [2048][512]
  // total ws use: 11,747,328 floats (~47 MB)

  hipMemsetAsync(st, 0, 9 * 16384 * sizeof(float), stream);

  k1_embed_gemm<<<dim3(32, 64), 256, 0, stream>>>(x, emb, Wxf, Wxb, bfv, bbv, Xf, Xb);

  for (int s = 0; s < 64; ++s) {
    const float* hfi = (s & 1) ? hfT1 : hfT0;
    float* hfo = (s & 1) ? hfT0 : hfT1;
    const float* hbi = (s & 1) ? hbT1 : hbT0;
    float* hbo = (s & 1) ? hbT0 : hbT1;
    k2_enc_step<<<256, 256, 0, stream>>>(Xf, Xb, Whf, Whb, hfi, hfo, hbi, hbo,
                                         cfT, cbT, a, s);
  }

  k5_aw1<<<256, 256, 0, stream>>>(a, W1, b1, aw1);

  for (int s = 0; s < 64; ++s) {
    const float* hdi = (s & 1) ? hdT1 : hdT0;
    float* hdo = (s & 1) ? hdT0 : hdT1;
    k3_attn<<<64, 256, 0, stream>>>(a, aw1, W1, W2, b2, hdi, ctx);
    k4_dec_step<<<256, 256, 0, stream>>>(ctx, hdi, Wxd, Whd, bd, hdo, cdT, Hs, s);
  }

  k6_logits<<<dim3(125, 32), 256, 0, stream>>>(Hs, Wo, bo, (float*)d_out);
  k7_softmax<<<256, 256, 0, stream>>>((float*)d_out);
}

// Round 2
// 4115.984 us; speedup vs baseline: 2.0184x; 2.0184x over previous
//
#include <hip/hip_runtime.h>
#include <hip/hip_bf16.h>
#include <cstdint>

typedef float f32x4 __attribute__((ext_vector_type(4)));
typedef __bf16 bf16x8 __attribute__((ext_vector_type(8)));

// ---------- bf16 pack helpers (RNE) ----------
__device__ __forceinline__ uint32_t bf1(float x) {
  uint32_t u = __float_as_uint(x);
  return (u + 0x7fffu + ((u >> 16) & 1u)) >> 16;
}
__device__ __forceinline__ uint32_t bpack(float lo, float hi) {
  return bf1(lo) | (bf1(hi) << 16);
}
__device__ __forceinline__ float blo(uint32_t u) { return __uint_as_float(u << 16); }
__device__ __forceinline__ float bhi(uint32_t u) { return __uint_as_float(u & 0xffff0000u); }
__device__ __forceinline__ float sigm(float x) { return 1.f / (1.f + __expf(-x)); }

#define GLOAD_LDS16(g, l)                                                     \
  __builtin_amdgcn_global_load_lds(                                           \
      (const __attribute__((address_space(1))) void*)(g),                     \
      (__attribute__((address_space(3))) void*)(l), 16, 0, 0)

// =====================================================================
// K0a: pack Whf/Whb -> per-block slabs [dir][blk][256 k2][16 c] u32
// =====================================================================
__global__ __launch_bounds__(256) void k0_enc(
    const float* __restrict__ Whf, const float* __restrict__ Whb,
    uint32_t* __restrict__ Wp)
{
  int p = blockIdx.x * 256 + threadIdx.x;        // 0..2^20-1
  int c = p & 15, k2 = (p >> 4) & 255, blk = (p >> 12) & 127, dir = p >> 19;
  const float* W = dir ? Whb : Whf;
  int col = (c >> 2) * 512 + blk * 4 + (c & 3);
  float v0 = W[(size_t)(2 * k2) * 2048 + col];
  float v1 = W[(size_t)(2 * k2 + 1) * 2048 + col];
  Wp[p] = bpack(v0, v1);
}

// =====================================================================
// K0b: pack [Wxd;Whd] -> per-block slabs [blk=256][768 k2][8 c] u32
// =====================================================================
__global__ __launch_bounds__(256) void k0_dec(
    const float* __restrict__ Wxd, const float* __restrict__ Whd,
    uint32_t* __restrict__ Wp)
{
  int p = blockIdx.x * 256 + threadIdx.x;        // 0..1572863
  int blk = p / 6144, r = p % 6144;
  int c = r & 7, k2 = r >> 3;
  int col = (c >> 1) * 512 + blk * 2 + (c & 1);
  int k = 2 * k2;
  float v0 = (k < 1024) ? Wxd[(size_t)k * 2048 + col] : Whd[(size_t)(k - 1024) * 2048 + col];
  float v1 = (k < 1024) ? Wxd[(size_t)(k + 1) * 2048 + col] : Whd[(size_t)(k - 1023) * 2048 + col];
  Wp[p] = bpack(v0, v1);
}

// =====================================================================
// K0c: pack W1[1024:,:10] -> [512][12] fp32 (padded)
// =====================================================================
__global__ __launch_bounds__(256) void k0_w1(
    const float* __restrict__ W1, float* __restrict__ W1p)
{
  int p = blockIdx.x * 256 + threadIdx.x;        // 0..6143
  int k = p / 12, j = p % 12;
  W1p[p] = (j < 10) ? W1[(size_t)(1024 + k) * 10 + j] : 0.f;
}

// =====================================================================
// K1: embedding gather + Xf = xe@Wxf + bf, Xb = xe@Wxb + bb (fp32 VALU)
// Output X[t][c][b]. grid (32 col-tiles, 64 t), 256 thr.
// =====================================================================
__global__ __launch_bounds__(256) void k1_embed_gemm(
    const int* __restrict__ x, const float* __restrict__ emb,
    const float* __restrict__ Wxf, const float* __restrict__ Wxb,
    const float* __restrict__ bfv, const float* __restrict__ bbv,
    float* __restrict__ Xf, float* __restrict__ Xb)
{
  __shared__ float As[32 * 260];
  __shared__ float Bs[32 * 128];
  __shared__ int xid[32];
  const int t = threadIdx.x;
  const int ty = blockIdx.y;
  const int c0 = blockIdx.x * 128;
  if (t < 32) xid[t] = x[t * 64 + ty];
  __syncthreads();
  for (int i = 0; i < 8; ++i) {
    int f4 = t + 256 * i;
    int r = f4 >> 6, k4 = (f4 & 63) << 2;
    float4 v = *(const float4*)(emb + (size_t)xid[r] * 256 + k4);
    *(float4*)(&As[r * 260 + k4]) = v;
  }
  const int isB = (c0 >= 2048);
  const float* Wsrc = isB ? Wxb : Wxf;
  const float* bias = isB ? bbv : bfv;
  const int cbase = c0 & 2047;
  float acc[4][4] = {};
  const int rq = t >> 5;
  const int cq = t & 31;
  for (int kc = 0; kc < 8; ++kc) {
    int k0 = kc * 32;
    __syncthreads();
    for (int i = 0; i < 4; ++i) {
      int f4 = t + 256 * i;
      int k = f4 >> 5, c4 = (f4 & 31) << 2;
      *(float4*)(&Bs[k * 128 + c4]) =
          *(const float4*)(Wsrc + (size_t)(k0 + k) * 2048 + cbase + c4);
    }
    __syncthreads();
#pragma unroll
    for (int kk = 0; kk < 32; ++kk) {
      float a0 = As[(4 * rq + 0) * 260 + k0 + kk];
      float a1 = As[(4 * rq + 1) * 260 + k0 + kk];
      float a2 = As[(4 * rq + 2) * 260 + k0 + kk];
      float a3 = As[(4 * rq + 3) * 260 + k0 + kk];
      float4 b = *(const float4*)(&Bs[kk * 128 + 4 * cq]);
      acc[0][0] += a0 * b.x; acc[0][1] += a0 * b.y; acc[0][2] += a0 * b.z; acc[0][3] += a0 * b.w;
      acc[1][0] += a1 * b.x; acc[1][1] += a1 * b.y; acc[1][2] += a1 * b.z; acc[1][3] += a1 * b.w;
      acc[2][0] += a2 * b.x; acc[2][1] += a2 * b.y; acc[2][2] += a2 * b.z; acc[2][3] += a2 * b.w;
      acc[3][0] += a3 * b.x; acc[3][1] += a3 * b.y; acc[3][2] += a3 * b.z; acc[3][3] += a3 * b.w;
    }
  }
  float* Xout = isB ? Xb : Xf;
  for (int i = 0; i < 4; ++i) {
    int c = cbase + 4 * cq + i;
    float bi = bias[c];
    for (int j = 0; j < 4; ++j) {
      int b_ = 4 * rq + j;
      Xout[((size_t)ty * 2048 + c) * 32 + b_] = acc[j][i] + bi;
    }
  }
}

// =====================================================================
// K2: one encoder step both dirs; h/W pre-packed bf16 pairs, pure-copy LDS.
// =====================================================================
__global__ __launch_bounds__(256) void k2_enc_step(
    const float* __restrict__ Xf, const float* __restrict__ Xb,
    const uint32_t* __restrict__ Wencp,
    const uint32_t* __restrict__ hfi, uint32_t* __restrict__ hfo,
    const uint32_t* __restrict__ hbi, uint32_t* __restrict__ hbo,
    float* __restrict__ cf, float* __restrict__ cb,
    float* __restrict__ a_out, int step)
{
  __shared__ uint32_t hTp[256 * 32];
  __shared__ uint32_t Wsp[256 * 16];
  __shared__ float zx[16 * 33];
  __shared__ float zbuf[32 * 17];
  __shared__ float hl[4 * 32];
  const int t = threadIdx.x;
  const int dir = blockIdx.x >> 7;
  const int blk = blockIdx.x & 127;
  const int u0 = blk * 4;
  const float* XF = dir ? Xb : Xf;
  const uint32_t* hin = dir ? hbi : hfi;
  uint32_t* hout = dir ? hbo : hfo;
  float* cst = dir ? cb : cf;
  const int ta = dir ? (63 - step) : step;
  const uint32_t* wsrc = Wencp + ((size_t)dir * 128 + blk) * 4096;

  for (int i = 0; i < 8; ++i) {
    int idx4 = t + 256 * i;
    *(uint4*)(&hTp[idx4 * 4]) = *(const uint4*)(hin + (size_t)idx4 * 4);
  }
  for (int i = 0; i < 4; ++i) {
    int idx4 = t + 256 * i;
    *(uint4*)(&Wsp[idx4 * 4]) = *(const uint4*)(wsrc + (size_t)idx4 * 4);
  }
  for (int i = 0; i < 2; ++i) {
    int p = t + 256 * i;
    int c = p >> 5, r = p & 31;
    int col = (c >> 2) * 512 + u0 + (c & 3);
    zx[c * 33 + r] = XF[((size_t)ta * 2048 + col) * 32 + r];
  }
  __syncthreads();
  const int r = t & 31, cc = t >> 5;
  float acc0 = zx[cc * 33 + r];
  float acc1 = zx[(cc + 8) * 33 + r];
#pragma unroll 8
  for (int k2 = 0; k2 < 256; ++k2) {
    uint32_t ua = hTp[k2 * 32 + r];
    uint32_t b0 = Wsp[k2 * 16 + cc];
    uint32_t b1 = Wsp[k2 * 16 + cc + 8];
    float a0 = blo(ua), a1 = bhi(ua);
    acc0 += a0 * blo(b0); acc0 += a1 * bhi(b0);
    acc1 += a0 * blo(b1); acc1 += a1 * bhi(b1);
  }
  zbuf[r * 17 + cc] = acc0;
  zbuf[r * 17 + cc + 8] = acc1;
  __syncthreads();
  if (t < 128) {
    int rr = t & 31, j = t >> 5;
    float zi = zbuf[rr * 17 + j];
    float zf = zbuf[rr * 17 + 4 + j];
    float zg = zbuf[rr * 17 + 8 + j];
    float zo = zbuf[rr * 17 + 12 + j];
    int u = u0 + j;
    float cold = cst[u * 32 + rr];
    float cn = sigm(zf) * cold + sigm(zi) * tanhf(zg);
    float h = sigm(zo) * tanhf(cn);
    cst[u * 32 + rr] = cn;
    a_out[((size_t)rr * 64 + ta) * 1024 + dir * 512 + u] = h;
    hl[j * 32 + rr] = h;
  }
  __syncthreads();
  if (t < 64) {
    int j = t >> 5, rr = t & 31;
    hout[(u0 / 2 + j) * 32 + rr] = bpack(hl[(2 * j) * 32 + rr], hl[(2 * j + 1) * 32 + rr]);
  }
}

// =====================================================================
// K5: aw1[m][j] = a[m]@W1[:1024,j] + b1[j] (fp32), padded to 16 cols.
// =====================================================================
__global__ __launch_bounds__(256) void k5_aw1(
    const float* __restrict__ a, const float* __restrict__ W1,
    const float* __restrict__ b1, float* __restrict__ aw1)
{
  __shared__ float ar[1024];
  __shared__ float ps[16 * 17];
  const int t = threadIdx.x;
  for (int m = blockIdx.x; m < 2048; m += gridDim.x) {
    __syncthreads();
    *(float4*)(&ar[t * 4]) = *(const float4*)(a + (size_t)m * 1024 + t * 4);
    __syncthreads();
    int j = t & 15, part = t >> 4;
    int jj = j < 10 ? j : 0;
    float s = 0.f;
#pragma unroll 8
    for (int k = part * 64; k < part * 64 + 64; ++k) s += ar[k] * W1[k * 10 + jj];
    ps[part * 17 + j] = s;
    __syncthreads();
    if (t < 16) {
      float sum = 0.f;
      if (t < 10) {
        for (int p = 0; p < 16; ++p) sum += ps[p * 17 + t];
        sum += b1[t];
      }
      aw1[m * 16 + t] = sum;
    }
  }
}

// =====================================================================
// K3: attention step: hW1 from packed hd, scores, softmax, ctx (packed out)
// =====================================================================
__global__ __launch_bounds__(256) void k3_attn(
    const float* __restrict__ a, const float* __restrict__ aw1,
    const float* __restrict__ W1p, const float* __restrict__ W2,
    const float* __restrict__ b2, const uint32_t* __restrict__ hdp,
    uint32_t* __restrict__ ctxp)
{
  __shared__ float W1s[512 * 12];
  __shared__ float ph[8 * 32 * 12];
  __shared__ float hw1[32 * 12];
  __shared__ float esc[32 * 65];
  __shared__ float pm[32 * 9];
  __shared__ float mrow[32], srow[32];
  __shared__ float w2s[12];
  __shared__ float ctxl[32 * 17];
  const int t = threadIdx.x;
  const int c0 = blockIdx.x * 16;
  for (int i = 0; i < 6; ++i) {
    int idx4 = t + 256 * i;
    *(float4*)(&W1s[idx4 * 4]) = *(const float4*)(W1p + (size_t)idx4 * 4);
  }
  if (t < 12) w2s[t] = (t < 10) ? W2[t] : 0.f;
  __syncthreads();
  {
    const int r = t & 31, kp = t >> 5;
    float acc[10] = {};
    for (int k2 = kp * 32; k2 < kp * 32 + 32; ++k2) {
      uint32_t u = hdp[k2 * 32 + r];
      float h0 = blo(u), h1 = bhi(u);
#pragma unroll
      for (int j = 0; j < 10; ++j)
        acc[j] += h0 * W1s[(2 * k2) * 12 + j] + h1 * W1s[(2 * k2 + 1) * 12 + j];
    }
#pragma unroll
    for (int j = 0; j < 10; ++j) ph[(kp * 32 + r) * 12 + j] = acc[j];
  }
  __syncthreads();
  if (t < 320) {
    int r = t & 31, j = t >> 5;
    float s = 0.f;
#pragma unroll
    for (int p = 0; p < 8; ++p) s += ph[(p * 32 + r) * 12 + j];
    hw1[r * 12 + j] = s;
  }
  __syncthreads();
  const float b2v = b2[0];
  for (int p = 0; p < 8; ++p) {
    int idx = t + 256 * p;
    int rr = idx >> 6, tt = idx & 63;
    const float4* aw = (const float4*)(aw1 + (size_t)idx * 16);
    float4 q0 = aw[0], q1 = aw[1], q2 = aw[2];
    const float* hw = &hw1[rr * 12];
    float e = b2v;
    e += tanhf(q0.x + hw[0]) * w2s[0];
    e += tanhf(q0.y + hw[1]) * w2s[1];
    e += tanhf(q0.z + hw[2]) * w2s[2];
    e += tanhf(q0.w + hw[3]) * w2s[3];
    e += tanhf(q1.x + hw[4]) * w2s[4];
    e += tanhf(q1.y + hw[5]) * w2s[5];
    e += tanhf(q1.z + hw[6]) * w2s[6];
    e += tanhf(q1.w + hw[7]) * w2s[7];
    e += tanhf(q2.x + hw[8]) * w2s[8];
    e += tanhf(q2.y + hw[9]) * w2s[9];
    esc[rr * 65 + tt] = fmaxf(e, 0.f);
  }
  __syncthreads();
  {
    int r = t & 31, part = t >> 5;
    float m = -1e30f;
    for (int i = 0; i < 8; ++i) m = fmaxf(m, esc[r * 65 + part * 8 + i]);
    pm[r * 9 + part] = m;
  }
  __syncthreads();
  if (t < 32) {
    float m = pm[t * 9];
    for (int p = 1; p < 8; ++p) m = fmaxf(m, pm[t * 9 + p]);
    mrow[t] = m;
  }
  __syncthreads();
  {
    int r = t & 31, part = t >> 5;
    float m = mrow[r];
    float s = 0.f;
    for (int i = 0; i < 8; ++i) s += __expf(esc[r * 65 + part * 8 + i] - m);
    pm[r * 9 + part] = s;
  }
  __syncthreads();
  if (t < 32) {
    float s = 0.f;
    for (int p = 0; p < 8; ++p) s += pm[t * 9 + p];
    srow[t] = 1.f / s;
  }
  __syncthreads();
  for (int p = 0; p < 8; ++p) {
    int idx = t + 256 * p;
    int rr = idx >> 6, tt = idx & 63;
    esc[rr * 65 + tt] = __expf(esc[rr * 65 + tt] - mrow[rr]) * srow[rr];
  }
  __syncthreads();
  {
    const int cl = t & 15, rr = t >> 4;
    const int c = c0 + cl;
    float acc0 = 0.f, acc1 = 0.f;
    for (int tt = 0; tt < 64; ++tt) {
      acc0 += esc[rr * 65 + tt] * a[((size_t)rr * 64 + tt) * 1024 + c];
      acc1 += esc[(rr + 16) * 65 + tt] * a[((size_t)(rr + 16) * 64 + tt) * 1024 + c];
    }
    ctxl[rr * 17 + cl] = acc0;
    ctxl[(rr + 16) * 17 + cl] = acc1;
  }
  __syncthreads();
  {
    int k2l = t >> 5, rr = t & 31;
    ctxp[(c0 / 2 + k2l) * 32 + rr] =
        bpack(ctxl[rr * 17 + 2 * k2l], ctxl[rr * 17 + 2 * k2l + 1]);
  }
}

// =====================================================================
// K4: decoder LSTM step (K=1536), all operands pre-packed, pure-copy LDS.
// Writes packed hd + bf16 HsB row.
// =====================================================================
__global__ __launch_bounds__(256) void k4_dec_step(
    const uint32_t* __restrict__ ctxp, const uint32_t* __restrict__ hdp_in,
    const uint32_t* __restrict__ Wdp, const float* __restrict__ bd,
    uint32_t* __restrict__ hdp_out, float* __restrict__ cd,
    ushort* __restrict__ HsB, int step)
{
  __shared__ uint32_t ATp[128 * 33];
  __shared__ uint32_t Wsp[768 * 8];
  __shared__ float zbuf[32 * 9];
  __shared__ float hl[2 * 32];
  const int t = threadIdx.x;
  const int u0 = blockIdx.x * 2;
  const uint32_t* wsrc = Wdp + (size_t)blockIdx.x * 6144;
  for (int i = 0; i < 6; ++i) {
    int idx4 = t + 256 * i;
    *(uint4*)(&Wsp[idx4 * 4]) = *(const uint4*)(wsrc + (size_t)idx4 * 4);
  }
  const int r = t & 31, cc = t >> 5;
  float acc = 0.f;
  for (int ch = 0; ch < 6; ++ch) {
    __syncthreads();
    int kb2 = ch * 128;
    const uint32_t* src = (ch < 4) ? (ctxp + (size_t)kb2 * 32)
                                   : (hdp_in + (size_t)(kb2 - 512) * 32);
    for (int i = 0; i < 16; ++i) {
      int p = t + 256 * i;
      int k2l = p >> 5, rr = p & 31;
      ATp[k2l * 33 + rr] = src[p];
    }
    __syncthreads();
    const uint32_t* wp = &Wsp[kb2 * 8];
#pragma unroll 8
    for (int k2 = 0; k2 < 128; ++k2) {
      uint32_t ua = ATp[k2 * 33 + r];
      uint32_t ub = wp[k2 * 8 + cc];
      acc += blo(ua) * blo(ub);
      acc += bhi(ua) * bhi(ub);
    }
  }
  int col = (cc >> 1) * 512 + u0 + (cc & 1);
  zbuf[r * 9 + cc] = acc + bd[col];
  __syncthreads();
  if (t < 64) {
    int rr = t & 31, j = t >> 5;
    int u = u0 + j;
    float zi = zbuf[rr * 9 + j];
    float zf = zbuf[rr * 9 + 2 + j];
    float zg = zbuf[rr * 9 + 4 + j];
    float zo = zbuf[rr * 9 + 6 + j];
    float cold = cd[u * 32 + rr];
    float cn = sigm(zf) * cold + sigm(zi) * tanhf(zg);
    float h = sigm(zo) * tanhf(cn);
    cd[u * 32 + rr] = cn;
    HsB[(size_t)(step * 32 + rr) * 512 + u] = (ushort)bf1(h);
    hl[j * 32 + rr] = h;
  }
  __syncthreads();
  if (t < 32) hdp_out[blockIdx.x * 32 + t] = bpack(hl[t], hl[32 + t]);
}

// =====================================================================
// K_woT: Wo[512][32000] fp32 -> WoT[32000][512] bf16 (LDS transpose)
// grid (500 n-tiles, 8 k-tiles)
// =====================================================================
__global__ __launch_bounds__(256) void k_woT(
    const float* __restrict__ Wo, ushort* __restrict__ WoT)
{
  __shared__ float tile[64 * 65];
  const int t = threadIdx.x;
  const int n0 = blockIdx.x * 64, k0 = blockIdx.y * 64;
  for (int i = 0; i < 16; ++i) {
    int p = t + 256 * i;
    int kk = p >> 6, nn = p & 63;
    tile[kk * 65 + nn] = Wo[(size_t)(k0 + kk) * 32000 + n0 + nn];
  }
  __syncthreads();
  for (int i = 0; i < 4; ++i) {
    int p = t + 256 * i;
    int nn = p >> 4, k4 = (p & 15) * 4;
    ushort4 o;
    o.x = (ushort)bf1(tile[(k4 + 0) * 65 + nn]);
    o.y = (ushort)bf1(tile[(k4 + 1) * 65 + nn]);
    o.z = (ushort)bf1(tile[(k4 + 2) * 65 + nn]);
    o.w = (ushort)bf1(tile[(k4 + 3) * 65 + nn]);
    *(ushort4*)(WoT + (size_t)(n0 + nn) * 512 + k0 + k4) = o;
  }
}

// =====================================================================
// K6: logits = HsB[2048,512] @ WoT^T + bo via MFMA bf16.
// 128x128 tile, BK=64, global_load_lds(16), XOR-swizzled k8 slots.
// grid (250 n-tiles, 16 m-tiles), 256 thr (4 waves, 2x2 of 64x64).
// =====================================================================
__global__ __launch_bounds__(256) void k6_logits_mfma(
    const ushort* __restrict__ HsB, const ushort* __restrict__ WoT,
    const float* __restrict__ bo, float* __restrict__ out)
{
  __shared__ ushort As[128 * 64];
  __shared__ ushort Bs[128 * 64];
  const int t = threadIdx.x;
  const int lane = t & 63, w = t >> 6;
  const int wr = w >> 1, wc = w & 1;
  const int m0 = blockIdx.y * 128, n0 = blockIdx.x * 128;
  const int lrow = lane >> 3, s = lane & 7;
  const int quad = lane >> 4, l15 = lane & 15;
  f32x4 acc[4][4] = {};
  for (int kc = 0; kc < 8; ++kc) {
    const int k0 = kc * 64;
    __syncthreads();
    for (int i = 0; i < 4; ++i) {
      int row = w * 32 + i * 8 + lrow;
      int k8 = s ^ (row & 7);
      GLOAD_LDS16(HsB + (size_t)(m0 + row) * 512 + k0 + k8 * 8,
                  As + (w * 32 + i * 8) * 64);
      GLOAD_LDS16(WoT + (size_t)(n0 + row) * 512 + k0 + k8 * 8,
                  Bs + (w * 32 + i * 8) * 64);
    }
    __syncthreads();
#pragma unroll
    for (int ks = 0; ks < 2; ++ks) {
      bf16x8 af[4], bfr[4];
      int kq = ks * 4 + quad;
#pragma unroll
      for (int mi = 0; mi < 4; ++mi) {
        int row = wr * 64 + mi * 16 + l15;
        int slot = kq ^ (row & 7);
        af[mi] = *(const bf16x8*)(As + row * 64 + slot * 8);
      }
#pragma unroll
      for (int ni = 0; ni < 4; ++ni) {
        int row = wc * 64 + ni * 16 + l15;
        int slot = kq ^ (row & 7);
        bfr[ni] = *(const bf16x8*)(Bs + row * 64 + slot * 8);
      }
#pragma unroll
      for (int mi = 0; mi < 4; ++mi)
#pragma unroll
        for (int ni = 0; ni < 4; ++ni)
          acc[mi][ni] = __builtin_amdgcn_mfma_f32_16x16x32_bf16(
              af[mi], bfr[ni], acc[mi][ni], 0, 0, 0);
    }
  }
#pragma unroll
  for (int mi = 0; mi < 4; ++mi) {
    int mbase = m0 + wr * 64 + mi * 16 + quad * 4;
#pragma unroll
    for (int reg = 0; reg < 4; ++reg) {
      int m = mbase + reg;
      size_t rowbase = ((size_t)(m & 31) * 64 + (m >> 5)) * 32000;
#pragma unroll
      for (int ni = 0; ni < 4; ++ni) {
        int n = n0 + wc * 64 + ni * 16 + l15;
        out[rowbase + n] = acc[mi][ni][reg] + bo[n];
      }
    }
  }
}

// =====================================================================
// K7: in-place row softmax over V=32000 (2048 rows).
// =====================================================================
__global__ __launch_bounds__(256) void k7_softmax(float* __restrict__ out)
{
  __shared__ float red[256];
  const int t = threadIdx.x;
  for (int row = blockIdx.x; row < 2048; row += gridDim.x) {
    float* p = out + (size_t)row * 32000;
    float m = -1e30f;
    for (int i = t; i < 8000; i += 256) {
      float4 v = *(const float4*)(p + i * 4);
      m = fmaxf(m, fmaxf(fmaxf(v.x, v.y), fmaxf(v.z, v.w)));
    }
    red[t] = m;
    __syncthreads();
    for (int s = 128; s > 0; s >>= 1) {
      if (t < s) red[t] = fmaxf(red[t], red[t + s]);
      __syncthreads();
    }
    m = red[0];
    __syncthreads();
    float sum = 0.f;
    for (int i = t; i < 8000; i += 256) {
      float4 v = *(const float4*)(p + i * 4);
      sum += __expf(v.x - m) + __expf(v.y - m) + __expf(v.z - m) + __expf(v.w - m);
    }
    red[t] = sum;
    __syncthreads();
    for (int s = 128; s > 0; s >>= 1) {
      if (t < s) red[t] += red[t + s];
      __syncthreads();
    }
    float inv = 1.f / red[0];
    __syncthreads();
    for (int i = t; i < 8000; i += 256) {
      float4 v = *(const float4*)(p + i * 4);
      v.x = __expf(v.x - m) * inv;
      v.y = __expf(v.y - m) * inv;
      v.z = __expf(v.z - m) * inv;
      v.w = __expf(v.w - m) * inv;
      *(float4*)(p + i * 4) = v;
    }
    __syncthreads();
  }
}

// =====================================================================
extern "C" void kernel_launch(void* const* d_in, const int* in_sizes, int n_in,
                              void* d_out, int out_size, void* d_ws, size_t ws_size,
                              hipStream_t stream)
{
  const int* x = (const int*)d_in[0];
  const float* emb = (const float*)d_in[1];
  const float* Wxf = (const float*)d_in[2];
  const float* Whf = (const float*)d_in[3];
  const float* bfv = (const float*)d_in[4];
  const float* Wxb = (const float*)d_in[5];
  const float* Whb = (const float*)d_in[6];
  const float* bbv = (const float*)d_in[7];
  const float* W1 = (const float*)d_in[8];
  const float* b1 = (const float*)d_in[9];
  const float* W2 = (const float*)d_in[10];
  const float* b2 = (const float*)d_in[11];
  const float* Wxd = (const float*)d_in[12];
  const float* Whd = (const float*)d_in[13];
  const float* bd = (const float*)d_in[14];
  const float* Wo = (const float*)d_in[15];
  const float* bo = (const float*)d_in[16];

  float* ws = (float*)d_ws;
  // layout (float offsets)
  float* c_f = ws + 0;
  float* c_b = ws + 16384;
  float* c_d = ws + 32768;
  uint32_t* hfp0 = (uint32_t*)(ws + 49152);
  uint32_t* hfp1 = hfp0 + 8192;
  uint32_t* hbp0 = (uint32_t*)(ws + 65536);
  uint32_t* hbp1 = hbp0 + 8192;
  uint32_t* hdp0 = (uint32_t*)(ws + 81920);
  uint32_t* hdp1 = hdp0 + 8192;
  uint32_t* ctxp = (uint32_t*)(ws + 98304);        // 16384 u32
  uint32_t* Wencp = (uint32_t*)(ws + 114688);      // 1,048,576 u32
  uint32_t* Wdp = (uint32_t*)(ws + 1163264);       // 1,572,864 u32
  float* W1p = ws + 2736128;                       // 6144
  float* aw1 = ws + 2742272;                       // 32768
  float* Xf = ws + 2775040;                        // 4,194,304
  float* Xb = Xf + 4194304;                        // 4,194,304
  float* a = Xb + 4194304;                         // 2,097,152 (ends 13,260,800)
  ushort* HsB = (ushort*)(ws + 13260800);          // 2048*512 bf16 (524,288 f32-equiv)
  ushort* WoT = (ushort*)Xf;                       // overlays Xf/Xb after encoder+decoder

  // zero recurrent states (c_f, c_b, c_d, packed h buffers)
  hipMemsetAsync(ws, 0, 98304 * sizeof(float), stream);

  k0_enc<<<4096, 256, 0, stream>>>(Whf, Whb, Wencp);
  k0_dec<<<6144, 256, 0, stream>>>(Wxd, Whd, Wdp);
  k0_w1<<<24, 256, 0, stream>>>(W1, W1p);

  k1_embed_gemm<<<dim3(32, 64), 256, 0, stream>>>(x, emb, Wxf, Wxb, bfv, bbv, Xf, Xb);

  for (int s = 0; s < 64; ++s) {
    const uint32_t* hfi = (s & 1) ? hfp1 : hfp0;
    uint32_t* hfo = (s & 1) ? hfp0 : hfp1;
    const uint32_t* hbi = (s & 1) ? hbp1 : hbp0;
    uint32_t* hbo = (s & 1) ? hbp0 : hbp1;
    k2_enc_step<<<256, 256, 0, stream>>>(Xf, Xb, Wencp, hfi, hfo, hbi, hbo,
                                         c_f, c_b, a, s);
  }

  k5_aw1<<<256, 256, 0, stream>>>(a, W1, b1, aw1);

  for (int s = 0; s < 64; ++s) {
    const uint32_t* hdi = (s & 1) ? hdp1 : hdp0;
    uint32_t* hdo = (s & 1) ? hdp0 : hdp1;
    k3_attn<<<64, 256, 0, stream>>>(a, aw1, W1p, W2, b2, hdi, ctxp);
    k4_dec_step<<<256, 256, 0, stream>>>(ctxp, hdi, Wdp, bd, hdo, c_d, HsB, s);
  }

  k_woT<<<dim3(500, 8), 256, 0, stream>>>(Wo, WoT);
  k6_logits_mfma<<<dim3(250, 16), 256, 0, stream>>>(HsB, WoT, bo, (float*)d_out);
  k7_softmax<<<256, 256, 0, stream>>>((float*)d_out);
}